// Round 12
// baseline (229.871 us; speedup 1.0000x reference)
//
#include <hip/hip_runtime.h>
#include <math.h>

// Problem constants
#define NPOS 40960      // T*H*W
#define TT 10
#define HH 64
#define WW 64
#define HWP 4096        // H*W
#define CIN 192
#define C3 576
#define NHEADS 4
#define CHD 48
#define HF 510
#define GNB 80          // gram n-chunks per head
#define GCHUNK 512      // 80*512 = 40960

typedef unsigned short u16;
typedef unsigned int   u32;
typedef __bf16 bf16x8 __attribute__((ext_vector_type(8)));
typedef __bf16 bf16x2 __attribute__((ext_vector_type(2)));
typedef float  f32x4  __attribute__((ext_vector_type(4)));
typedef u16    u16x8  __attribute__((ext_vector_type(8)));
typedef u16    u16x4  __attribute__((ext_vector_type(4)));
typedef u32    u32x4  __attribute__((ext_vector_type(4)));
typedef u32    u32x2  __attribute__((ext_vector_type(2)));

__device__ __forceinline__ float b2f(u16 u) {
    return __uint_as_float(((unsigned int)u) << 16);
}
// integer RNE: used for block-uniform values (stays on SALU -> weights in SGPR)
__device__ __forceinline__ u16 f2b(float f) {
    unsigned int i = __float_as_uint(f);
    unsigned int r = (i + 0x7FFFu + ((i >> 16) & 1u)) >> 16;   // RNE
    return (u16)r;
}
// HW cvt: per-lane stores; compiler pairs adjacent casts into v_cvt_pk_bf16_f32 (RNE)
__device__ __forceinline__ u16 f2bh(float f) {
    return __builtin_bit_cast(u16, static_cast<__bf16>(f));
}
// branch-free gelu: Abramowitz-Stegun 7.1.26 erf (|abs err| <= 1.5e-7, far below
// bf16 rounding). Uses native v_rcp_f32 + v_exp_f32 (~17 VALU, no branches).
__device__ __forceinline__ float gelu_fast(float v) {
    float z = fabsf(v) * 0.70710678118654752f;
    float d = fmaf(0.3275911f, z, 1.0f);
#if __has_builtin(__builtin_amdgcn_rcpf)
    float t = __builtin_amdgcn_rcpf(d);
#else
    float t = 1.0f / d;
#endif
    float p = fmaf(1.061405429f, t, -1.453152027f);
    p = fmaf(p, t, 1.421413741f);
    p = fmaf(p, t, -0.284496736f);
    p = fmaf(p, t, 0.254829592f);
    p = p * t;
    float e = __expf(-z * z);
    float E = fmaf(-p, e, 1.0f);          // erf(z), z >= 0
    return 0.5f * v * (1.0f + copysignf(E, v));
}

// packed bf16 pair dot-product with f32 accumulate; HW v_dot2_f32_bf16 if available
__device__ __forceinline__ float dot2bf(u32 a, u32 b, float c) {
#if __has_builtin(__builtin_amdgcn_fdot2_f32_bf16)
    return __builtin_amdgcn_fdot2_f32_bf16(
        __builtin_bit_cast(bf16x2, a), __builtin_bit_cast(bf16x2, b), c, false);
#else
    float a0 = b2f((u16)(a & 0xffffu)), a1 = b2f((u16)(a >> 16));
    float b0 = b2f((u16)(b & 0xffffu)), b1 = b2f((u16)(b >> 16));
    return fmaf(a1, b1, fmaf(a0, b0, c));
#endif
}
__device__ __forceinline__ u32 alignp(u32 hi, u32 lo) {
#if __has_builtin(__builtin_amdgcn_alignbit)
    return __builtin_amdgcn_alignbit(hi, lo, 16);
#else
    return (lo >> 16) | (hi << 16);
#endif
}

// VALU lane-neighbor exchange via DPP. row_shr:1 (0x111): dst lane n = src lane n-1;
// row_shl:1 (0x101): dst lane n = src lane n+1. bound_ctrl=1 zeroes at the 16-lane
// row boundaries.
__device__ __forceinline__ u32 dpp_prev(u32 v) {
#if __has_builtin(__builtin_amdgcn_update_dpp)
    return (u32)__builtin_amdgcn_update_dpp(0, (int)v, 0x111, 0xF, 0xF, true);
#else
    int l = (int)(threadIdx.x & 63);
    u32 r = __shfl(v, l - 1);
    return ((l & 15) == 0) ? 0u : r;
#endif
}
__device__ __forceinline__ u32 dpp_next(u32 v) {
#if __has_builtin(__builtin_amdgcn_update_dpp)
    return (u32)__builtin_amdgcn_update_dpp(0, (int)v, 0x101, 0xF, 0xF, true);
#else
    int l = (int)(threadIdx.x & 63);
    u32 r = __shfl(v, l + 1);
    return ((l & 15) == 15) ? 0u : r;
#endif
}
__device__ __forceinline__ u32 dpp_prev8(u32 v, bool edge) {
    u32 r = dpp_prev(v);
    return edge ? 0u : r;
}
__device__ __forceinline__ u32 dpp_next8(u32 v, bool edge) {
    u32 r = dpp_next(v);
    return edge ? 0u : r;
}

// async global->LDS, 16B per lane; lds base must be wave-uniform
#define GLD_LDS16(g, l) __builtin_amdgcn_global_load_lds( \
    (const __attribute__((address_space(1))) void*)(g), \
    (__attribute__((address_space(3))) void*)(l), 16, 0, 0)

// ---------------- combined weight convert fp32 -> bf16 with zero padding ----------------
#define CVT_N1 (640 * 192)
#define CVT_N2 (1024 * 192)
#define CVT_N3 (256 * 512)
__global__ void cvtw_k(const float* __restrict__ qkv_w, const float* __restrict__ pin_w,
                       const float* __restrict__ pout_w,
                       u16* __restrict__ qkv_wb, u16* __restrict__ pin_wb,
                       u16* __restrict__ pout_wb) {
    int idx = blockIdx.x * 256 + threadIdx.x;
    if (idx < CVT_N1) {
        int r = idx / 192, c = idx % 192;
        qkv_wb[idx] = f2bh(r < 576 ? qkv_w[r * 192 + c] : 0.f);
    } else if (idx < CVT_N1 + CVT_N2) {
        int k = idx - CVT_N1;
        int r = k / 192, c = k % 192;
        pin_wb[k] = f2bh(r < 1020 ? pin_w[r * 192 + c] : 0.f);
    } else if (idx < CVT_N1 + CVT_N2 + CVT_N3) {
        int k = idx - CVT_N1 - CVT_N2;
        int r = k / 512, c = k % 512;
        pout_wb[k] = f2bh((r < 192 && c < 510) ? pout_w[r * 510 + c] : 0.f);
    }
}

// ---------------- fused LN (over C) + transpose to [N][192] bf16 ----------------
template<typename InT>
__global__ __launch_bounds__(256) void lnt_k(const InT* __restrict__ X,
                                             const float* __restrict__ w,
                                             const float* __restrict__ b,
                                             u16* __restrict__ Xt) {
    __shared__ float sm[CIN][65];
    __shared__ float ps[4][64], ps2[4][64];
    __shared__ float smean[64], srstd[64];
    __shared__ float sw[CIN], sb[CIN];
    const int tid = threadIdx.x;
    const int n0 = blockIdx.x * 64;
    if (tid < CIN) { sw[tid] = w[tid]; sb[tid] = b[tid]; }
    if constexpr (sizeof(InT) == 4) {
        #pragma unroll
        for (int i = 0; i < 12; ++i) {
            int e = i * 256 + tid;
            int c = e >> 4, p4 = (e & 15) * 4;
            float4 v = *(const float4*)((const float*)X + (size_t)c * NPOS + n0 + p4);
            sm[c][p4 + 0] = v.x; sm[c][p4 + 1] = v.y;
            sm[c][p4 + 2] = v.z; sm[c][p4 + 3] = v.w;
        }
    } else {
        #pragma unroll
        for (int i = 0; i < 6; ++i) {
            int e = i * 256 + tid;
            int c = e >> 3, p8 = (e & 7) * 8;
            u16x8 v = *(const u16x8*)((const u16*)X + (size_t)c * NPOS + n0 + p8);
            #pragma unroll
            for (int j = 0; j < 8; ++j) sm[c][p8 + j] = b2f(v[j]);
        }
    }
    __syncthreads();
    int g = tid >> 6, nn = tid & 63;
    float s = 0.f, s2 = 0.f;
    for (int c = g * 48; c < g * 48 + 48; ++c) {
        float v = sm[c][nn];
        s += v; s2 += v * v;
    }
    ps[g][nn] = s; ps2[g][nn] = s2;
    __syncthreads();
    if (g == 0) {
        float t = ps[0][nn] + ps[1][nn] + ps[2][nn] + ps[3][nn];
        float t2 = ps2[0][nn] + ps2[1][nn] + ps2[2][nn] + ps2[3][nn];
        float m = t / CIN;
        float var = t2 / CIN - m * m;
        smean[nn] = m;
        srstd[nn] = rsqrtf(var + 1e-5f);
    }
    __syncthreads();
    #pragma unroll
    for (int i = 0; i < 6; ++i) {
        int e = i * 256 + tid;
        int nl = e / 24, cg = e % 24;
        int c0 = cg * 8;
        float m = smean[nl], rs_ = srstd[nl];
        u16x8 o;
        #pragma unroll
        for (int j = 0; j < 8; ++j) {
            float v = (sm[c0 + j][nl] - m) * rs_ * sw[c0 + j] + sb[c0 + j];
            o[j] = f2bh(v);
        }
        *(u16x8*)(Xt + (size_t)(n0 + nl) * CIN + c0) = o;
    }
}

// ---------------- MFMA GEMM, LDS double-buffered (m97 structure) ----------------
// out[o][n] = sum_k A[o][k]*Bt[n][k] (+resid). Tile 128x128, BK=32. Bt is [N][KP].
// Grid is dim3(O_blocks, N_blocks): m varies FASTEST in dispatch order, so the
// 5-8 consecutive blocks sharing one 128-wide B-tile are co-resident on an XCD
// and hit L2 instead of re-pulling B from L3/HBM each m-round.
template<int KP, typename OutT, typename ResT, bool RESID>
__global__ __launch_bounds__(256) void gemm_mfma_k(
    const u16* __restrict__ A, const u16* __restrict__ Bt, int O,
    const ResT* __restrict__ resid, OutT* __restrict__ outp)
{
    constexpr int NT = KP / 32;
    __shared__ u16 As[2][128 * 32];
    __shared__ u16 Bs[2][128 * 32];
    const int tid  = threadIdx.x;
    const int lane = tid & 63;
    const int wv   = tid >> 6;
    const int lo = lane & 15, hi = lane >> 4;
    const int m_blk = blockIdx.x * 128;    // m fastest
    const int n_blk = blockIdx.y * 128;

    int bb0 = (0 * 4 + wv) * 1024 + lane * 16;
    int bb1 = (1 * 4 + wv) * 1024 + lane * 16;
    const int r0 = bb0 >> 6, c80 = (bb0 >> 4) & 3;
    const int r1 = bb1 >> 6, c81 = (bb1 >> 4) & 3;

    auto stage = [&](int buf, int k0) {
        GLD_LDS16(A  + (size_t)(m_blk + r0) * KP + k0 + c80 * 8, (char*)&As[buf][0] + (0 * 4 + wv) * 1024);
        GLD_LDS16(A  + (size_t)(m_blk + r1) * KP + k0 + c81 * 8, (char*)&As[buf][0] + (1 * 4 + wv) * 1024);
        GLD_LDS16(Bt + (size_t)(n_blk + r0) * KP + k0 + c80 * 8, (char*)&Bs[buf][0] + (0 * 4 + wv) * 1024);
        GLD_LDS16(Bt + (size_t)(n_blk + r1) * KP + k0 + c81 * 8, (char*)&Bs[buf][0] + (1 * 4 + wv) * 1024);
    };

    f32x4 acc[4][4];
    const f32x4 zero = {0.f, 0.f, 0.f, 0.f};
    #pragma unroll
    for (int mt = 0; mt < 4; ++mt)
        #pragma unroll
        for (int nt = 0; nt < 4; ++nt) acc[mt][nt] = zero;

    stage(0, 0);
    __syncthreads();

    #pragma unroll
    for (int t = 0; t < NT; ++t) {
        if (t + 1 < NT) stage((t + 1) & 1, (t + 1) * 32);
        const u16* Ab = &As[t & 1][0] + (wv & 1) * 64 * 32;
        const u16* Bb = &Bs[t & 1][0] + (wv >> 1) * 64 * 32;
        bf16x8 a[4], b[4];
        #pragma unroll
        for (int q = 0; q < 4; ++q) {
            a[q] = *(const bf16x8*)(Ab + (q * 16 + lo) * 32 + hi * 8);
            b[q] = *(const bf16x8*)(Bb + (q * 16 + lo) * 32 + hi * 8);
        }
        #pragma unroll
        for (int mt = 0; mt < 4; ++mt)
            #pragma unroll
            for (int nt = 0; nt < 4; ++nt)
                acc[mt][nt] = __builtin_amdgcn_mfma_f32_16x16x32_bf16(
                    a[mt], b[nt], acc[mt][nt], 0, 0, 0);
        __syncthreads();
    }

    const int m_base = m_blk + (wv & 1) * 64;
    const int n_base = n_blk + (wv >> 1) * 64;
    #pragma unroll
    for (int mt = 0; mt < 4; ++mt) {
        #pragma unroll
        for (int r = 0; r < 4; ++r) {
            int m = m_base + mt * 16 + hi * 4 + r;
            if (m < O) {
                size_t rowoff = (size_t)m * NPOS;
                #pragma unroll
                for (int nt = 0; nt < 4; ++nt) {
                    int n = n_base + nt * 16 + lo;
                    float v = acc[mt][nt][r];
                    if (RESID) {
                        if constexpr (sizeof(ResT) == 2) v += b2f(((const u16*)resid)[rowoff + n]);
                        else                             v += ((const float*)resid)[rowoff + n];
                    }
                    if constexpr (sizeof(OutT) == 2) outp[rowoff + n] = (OutT)f2bh(v);
                    else                             outp[rowoff + n] = (OutT)v;
                }
            }
        }
    }
}

// ---------------- MFMA GEMM with in-kernel B transpose (B given as [K][N]) --------
// out[o][n] = sum_k A[o][k]*B[k][n] (+resid). Per K-step the 32x128 B-tile is read
// COALESCED from [K][N] rows, written transposed into LDS with k-block XOR swizzle.
// Grid is dim3(O_blocks, N_blocks): m fastest (B-tile L2 reuse, see gemm_mfma_k).
template<int KP, typename OutT, typename ResT, bool RESID>
__global__ __launch_bounds__(256) void gemm_bt_k(
    const u16* __restrict__ A, const u16* __restrict__ Bkn, int O,
    const ResT* __restrict__ resid, OutT* __restrict__ outp)
{
    constexpr int NT = KP / 32;
    __shared__ u16 As[2][128 * 32];
    __shared__ u16 Bs[2][128 * 32];
    const int tid  = threadIdx.x;
    const int lane = tid & 63;
    const int wv   = tid >> 6;
    const int lo = lane & 15, hi = lane >> 4;
    const int m_blk = blockIdx.x * 128;    // m fastest
    const int n_blk = blockIdx.y * 128;

    int bb0 = (0 * 4 + wv) * 1024 + lane * 16;
    int bb1 = (1 * 4 + wv) * 1024 + lane * 16;
    const int r0 = bb0 >> 6, c80 = (bb0 >> 4) & 3;
    const int r1 = bb1 >> 6, c81 = (bb1 >> 4) & 3;
    auto stageA = [&](int buf, int k0) {
        GLD_LDS16(A + (size_t)(m_blk + r0) * KP + k0 + c80 * 8, (char*)&As[buf][0] + (0 * 4 + wv) * 1024);
        GLD_LDS16(A + (size_t)(m_blk + r1) * KP + k0 + c81 * 8, (char*)&As[buf][0] + (1 * 4 + wv) * 1024);
    };

    const int kp2 = (tid & 15) * 2;        // 0,2,..,30
    const int nf  = (tid >> 4) * 8;        // 0..120
    const int kb  = kp2 >> 3;              // k-block 0..3
    const int klo = kp2 & 7;               // even
    u16x8 bv0, bv1;
    auto loadB = [&](int k0) {
        const u16* sp = Bkn + (size_t)(k0 + kp2) * NPOS + n_blk + nf;
        bv0 = *(const u16x8*)(sp);
        bv1 = *(const u16x8*)(sp + NPOS);
    };
    auto writeB = [&](int buf) {
        #pragma unroll
        for (int i = 0; i < 8; ++i) {
            int n = nf + i;
            int idx = n * 32 + ((kb ^ ((n >> 4) & 3)) << 3) + klo;
            u32 pk = (u32)bv0[i] | ((u32)bv1[i] << 16);
            *(u32*)&Bs[buf][idx] = pk;
        }
    };

    f32x4 acc[4][4];
    const f32x4 zero = {0.f, 0.f, 0.f, 0.f};
    #pragma unroll
    for (int mt = 0; mt < 4; ++mt)
        #pragma unroll
        for (int nt = 0; nt < 4; ++nt) acc[mt][nt] = zero;

    stageA(0, 0);
    loadB(0);
    writeB(0);
    __syncthreads();

    #pragma unroll
    for (int t = 0; t < NT; ++t) {
        if (t + 1 < NT) { stageA((t + 1) & 1, (t + 1) * 32); loadB((t + 1) * 32); }
        const u16* Ab = &As[t & 1][0] + (wv & 1) * 64 * 32;
        const u16* Bb = &Bs[t & 1][0] + (wv >> 1) * 64 * 32;
        bf16x8 a[4], b[4];
        #pragma unroll
        for (int q = 0; q < 4; ++q) {
            a[q] = *(const bf16x8*)(Ab + (q * 16 + lo) * 32 + hi * 8);
            b[q] = *(const bf16x8*)(Bb + (q * 16 + lo) * 32 + ((hi ^ (q & 3)) * 8));
        }
        #pragma unroll
        for (int mt = 0; mt < 4; ++mt)
            #pragma unroll
            for (int nt = 0; nt < 4; ++nt)
                acc[mt][nt] = __builtin_amdgcn_mfma_f32_16x16x32_bf16(
                    a[mt], b[nt], acc[mt][nt], 0, 0, 0);
        if (t + 1 < NT) writeB((t + 1) & 1);
        __syncthreads();
    }

    const int m_base = m_blk + (wv & 1) * 64;
    const int n_base = n_blk + (wv >> 1) * 64;
    #pragma unroll
    for (int mt = 0; mt < 4; ++mt) {
        #pragma unroll
        for (int r = 0; r < 4; ++r) {
            int m = m_base + mt * 16 + hi * 4 + r;
            if (m < O) {
                size_t rowoff = (size_t)m * NPOS;
                #pragma unroll
                for (int nt = 0; nt < 4; ++nt) {
                    int n = n_base + nt * 16 + lo;
                    float v = acc[mt][nt][r];
                    if (RESID) {
                        if constexpr (sizeof(ResT) == 2) v += b2f(((const u16*)resid)[rowoff + n]);
                        else                             v += ((const float*)resid)[rowoff + n];
                    }
                    if constexpr (sizeof(OutT) == 2) outp[rowoff + n] = (OutT)f2bh(v);
                    else                             outp[rowoff + n] = (OutT)v;
                }
            }
        }
    }
}

// ---------------- Depthwise 3x3x3 conv, padding=1, bf16 in/out ----------------
// Equilibrium form (8 structural variants all land at 46-52us): DPP neighbor
// exchange, 2-slice-deep prefetch, no in-loop barriers, fused norm partials.
__global__ __launch_bounds__(256) void dwconv_k(const u16* __restrict__ in,
                                                u16* __restrict__ outp,
                                                const float* __restrict__ wgt,
                                                float* __restrict__ nrm2)
{
    __shared__ float red[256];
    const int lane = threadIdx.x & 63;
    const int wv   = threadIdx.x >> 6;
    const int c    = blockIdx.x >> 1;
    const int hb   = blockIdx.x & 1;
    const int h    = hb * 32 + wv * 8 + (lane >> 3);
    const int w0c  = (lane & 7) * 8;
    const bool wl0 = (lane & 7) == 0;
    const bool wl7 = (lane & 7) == 7;
    const bool hup = (h > 0), hdn = (h < HH - 1);
    u32 W01[9], W2h[9];
    {
        const float* wc = wgt + c * 27;
        #pragma unroll
        for (int i = 0; i < 9; ++i) {
            float a = wc[i * 3 + 0], b = wc[i * 3 + 1], d = wc[i * 3 + 2];
            W01[i] = (u32)f2b(a) | ((u32)f2b(b) << 16);
            W2h[i] = ((u32)f2b(d)) << 16;
        }
    }
    const u16* base = in   + (size_t)c * (TT * HWP);
    u16*       ob   = outp + (size_t)c * (TT * HWP);

    u32x4 zv = {0u, 0u, 0u, 0u};
    u32x4 ld[3][3];
    auto issue = [&](int ph, int ts) {
        const u16* rp = base + (size_t)ts * HWP + h * WW + w0c;
        ld[ph][0] = hup ? *(const u32x4*)(rp - WW) : zv;
        ld[ph][1] = *(const u32x4*)(rp);
        ld[ph][2] = hdn ? *(const u32x4*)(rp + WW) : zv;
    };

    float acc[3][8];
    #pragma unroll
    for (int o_ = 0; o_ < 3; ++o_)
        #pragma unroll
        for (int j = 0; j < 8; ++j) acc[o_][j] = 0.f;
    float sq = 0.f;

    issue(0, 0);
    issue(1, 1);
    #pragma unroll
    for (int ts = 0; ts < TT; ++ts) {
        const int cb = ts % 3;
        if (ts + 2 < TT) issue((ts + 2) % 3, ts + 2);
        #pragma unroll
        for (int dh = 0; dh < 3; ++dh) {
            u32 P0 = ld[cb][dh][0], P1 = ld[cb][dh][1];
            u32 P2 = ld[cb][dh][2], P3 = ld[cb][dh][3];
            u32 Pm = dpp_prev8(P3, wl0);
            u32 Pp = dpp_next8(P0, wl7);
            u32 S0 = alignp(P0, Pm), S1 = alignp(P1, P0);
            u32 S2 = alignp(P2, P1), S3 = alignp(P3, P2);
            u32 S4 = alignp(Pp, P3);
            #pragma unroll
            for (int tp = 0; tp < 3; ++tp) {
                int o_;
                if (tp == 2) { if (ts < 1) continue; o_ = (ts - 1) % 3; }
                else if (tp == 1) { o_ = ts % 3; }
                else { if (ts + 1 >= TT) continue; o_ = (ts + 1) % 3; }
                const u32 wA = W01[tp * 3 + dh], wB = W2h[tp * 3 + dh];
                float* ap = acc[o_];
                ap[0] = dot2bf(S0, wA, ap[0]); ap[0] = dot2bf(P0, wB, ap[0]);
                ap[1] = dot2bf(P0, wA, ap[1]); ap[1] = dot2bf(S1, wB, ap[1]);
                ap[2] = dot2bf(S1, wA, ap[2]); ap[2] = dot2bf(P1, wB, ap[2]);
                ap[3] = dot2bf(P1, wA, ap[3]); ap[3] = dot2bf(S2, wB, ap[3]);
                ap[4] = dot2bf(S2, wA, ap[4]); ap[4] = dot2bf(P2, wB, ap[4]);
                ap[5] = dot2bf(P2, wA, ap[5]); ap[5] = dot2bf(S3, wB, ap[5]);
                ap[6] = dot2bf(S3, wA, ap[6]); ap[6] = dot2bf(P3, wB, ap[6]);
                ap[7] = dot2bf(P3, wA, ap[7]); ap[7] = dot2bf(S4, wB, ap[7]);
            }
        }
        if (ts >= 1) {
            const int o_ = (ts - 1) % 3;
            u16x8 o;
            #pragma unroll
            for (int j = 0; j < 8; ++j) {
                float v = acc[o_][j];
                sq = fmaf(v, v, sq);
                o[j] = f2bh(v);
            }
            *(u16x8*)(ob + (size_t)(ts - 1) * HWP + h * WW + w0c) = o;
            #pragma unroll
            for (int j = 0; j < 8; ++j) acc[o_][j] = 0.f;
        }
    }
    {
        const int o_ = (TT - 1) % 3;
        u16x8 o;
        #pragma unroll
        for (int j = 0; j < 8; ++j) {
            float v = acc[o_][j];
            sq = fmaf(v, v, sq);
            o[j] = f2bh(v);
        }
        *(u16x8*)(ob + (size_t)(TT - 1) * HWP + h * WW + w0c) = o;
    }
    if (nrm2) {
        red[threadIdx.x] = sq;
        __syncthreads();
        for (int off = 128; off > 0; off >>= 1) {
            if (threadIdx.x < off) red[threadIdx.x] += red[threadIdx.x + off];
            __syncthreads();
        }
        if (threadIdx.x == 0) nrm2[c * 2 + hb] = red[0];
    }
}

// ---------------- FFN: fused depthwise conv pair + gelu gate, BARRIER-FREE ----------------
// cpr in 0..511: cpr >= HF writes zero rows (510,511) so the padded K=512 GEMM
// staging reads zeros.
__global__ __launch_bounds__(256) void dwconv_glu3_k(const u16* __restrict__ in,
                                                     u16* __restrict__ gout,
                                                     const float* __restrict__ wgt)
{
    const int lane = threadIdx.x & 63;
    const int wv   = threadIdx.x >> 6;     // 0..3
    const int cpr  = blockIdx.x >> 2;      // 0..511
    const int hb   = blockIdx.x & 3;
    const int h    = hb * 16 + wv * 4 + (lane >> 4);
    const int w0c  = (lane & 15) * 4;
    u16* ob = gout + (size_t)cpr * (TT * HWP);
    if (cpr >= HF) {                       // zero-pad rows 510,511
        u16x4 z = {0, 0, 0, 0};
        #pragma unroll
        for (int ts = 0; ts < TT; ++ts)
            *(u16x4*)(ob + (size_t)ts * HWP + h * WW + w0c) = z;
        return;
    }
    const bool hup = (h > 0), hdn = (h < HH - 1);

    u32 W01[2][9], W2h[2][9];
    #pragma unroll
    for (int ch = 0; ch < 2; ++ch) {
        const float* wc = wgt + (size_t)(cpr + ch * HF) * 27;
        #pragma unroll
        for (int i = 0; i < 9; ++i) {
            float a = wc[i * 3 + 0], b = wc[i * 3 + 1], d = wc[i * 3 + 2];
            W01[ch][i] = (u32)f2b(a) | ((u32)f2b(b) << 16);
            W2h[ch][i] = ((u32)f2b(d)) << 16;
        }
    }
    const u16* base0 = in + (size_t)cpr * (TT * HWP);
    const u16* base1 = in + (size_t)(cpr + HF) * (TT * HWP);

    u32x2 zv = {0u, 0u};
    u32x2 ld[2][3][3];
    auto issue = [&](int ph, int ts) {
        const u16* rp0 = base0 + (size_t)ts * HWP + h * WW + w0c;
        ld[0][ph][0] = hup ? *(const u32x2*)(rp0 - WW) : zv;
        ld[0][ph][1] = *(const u32x2*)(rp0);
        ld[0][ph][2] = hdn ? *(const u32x2*)(rp0 + WW) : zv;
        const u16* rp1 = base1 + (size_t)ts * HWP + h * WW + w0c;
        ld[1][ph][0] = hup ? *(const u32x2*)(rp1 - WW) : zv;
        ld[1][ph][1] = *(const u32x2*)(rp1);
        ld[1][ph][2] = hdn ? *(const u32x2*)(rp1 + WW) : zv;
    };

    float acc[2][3][4];
    #pragma unroll
    for (int ch = 0; ch < 2; ++ch)
        #pragma unroll
        for (int o_ = 0; o_ < 3; ++o_)
            #pragma unroll
            for (int j = 0; j < 4; ++j) acc[ch][o_][j] = 0.f;

    auto emit = [&](int ots) {
        const int o_ = ots % 3;
        u16x4 o;
        #pragma unroll
        for (int j = 0; j < 4; ++j)
            o[j] = f2bh(gelu_fast(acc[0][o_][j]) * acc[1][o_][j]);
        *(u16x4*)(ob + (size_t)ots * HWP + h * WW + w0c) = o;
        #pragma unroll
        for (int j = 0; j < 4; ++j) { acc[0][o_][j] = 0.f; acc[1][o_][j] = 0.f; }
    };

    issue(0, 0);
    issue(1, 1);
    #pragma unroll
    for (int ts = 0; ts < TT; ++ts) {
        const int cb = ts % 3;
        if (ts + 2 < TT) issue((ts + 2) % 3, ts + 2);
        #pragma unroll
        for (int ch = 0; ch < 2; ++ch) {
            #pragma unroll
            for (int dh = 0; dh < 3; ++dh) {
                u32 P0 = ld[ch][cb][dh][0], P1 = ld[ch][cb][dh][1];
                u32 Pm = dpp_prev(P1);
                u32 Pp = dpp_next(P0);
                u32 S0 = alignp(P0, Pm), S1 = alignp(P1, P0), S2 = alignp(Pp, P1);
                #pragma unroll
                for (int tp = 0; tp < 3; ++tp) {
                    int o_;
                    if (tp == 2) { if (ts < 1) continue; o_ = (ts - 1) % 3; }
                    else if (tp == 1) { o_ = ts % 3; }
                    else { if (ts + 1 >= TT) continue; o_ = (ts + 1) % 3; }
                    const u32 wA = W01[ch][tp * 3 + dh], wB = W2h[ch][tp * 3 + dh];
                    float* ap = acc[ch][o_];
                    ap[0] = dot2bf(S0, wA, ap[0]); ap[0] = dot2bf(P0, wB, ap[0]);
                    ap[1] = dot2bf(P0, wA, ap[1]); ap[1] = dot2bf(S1, wB, ap[1]);
                    ap[2] = dot2bf(S1, wA, ap[2]); ap[2] = dot2bf(P1, wB, ap[2]);
                    ap[3] = dot2bf(P1, wA, ap[3]); ap[3] = dot2bf(S2, wB, ap[3]);
                }
            }
        }
        if (ts >= 1) emit(ts - 1);
    }
    emit(TT - 1);
}

// ---------------- gram partials via MFMA: part[blk][48][48] = q_chunk k_chunk^T ----------------
__global__ __launch_bounds__(64) void gram_k(const u16* __restrict__ qkv,
                                             float* __restrict__ part) {
    const int h  = blockIdx.x / GNB;
    const int nb = blockIdx.x % GNB;
    const int lane = threadIdx.x;
    const int lo = lane & 15, hi = lane >> 4;
    const u16* qp = qkv + (size_t)(h * CHD) * NPOS + (size_t)nb * GCHUNK + hi * 8;
    const u16* kp = qkv + (size_t)(CIN + h * CHD) * NPOS + (size_t)nb * GCHUNK + hi * 8;
    f32x4 acc[3][3];
    const f32x4 zero = {0.f, 0.f, 0.f, 0.f};
    #pragma unroll
    for (int mt = 0; mt < 3; ++mt)
        #pragma unroll
        for (int nt = 0; nt < 3; ++nt) acc[mt][nt] = zero;
    #pragma unroll
    for (int ks = 0; ks < GCHUNK; ks += 32) {
        bf16x8 a[3], b[3];
        #pragma unroll
        for (int t = 0; t < 3; ++t) {
            a[t] = *(const bf16x8*)(qp + (size_t)(t * 16 + lo) * NPOS + ks);
            b[t] = *(const bf16x8*)(kp + (size_t)(t * 16 + lo) * NPOS + ks);
        }
        #pragma unroll
        for (int mt = 0; mt < 3; ++mt)
            #pragma unroll
            for (int nt = 0; nt < 3; ++nt)
                acc[mt][nt] = __builtin_amdgcn_mfma_f32_16x16x32_bf16(
                    a[mt], b[nt], acc[mt][nt], 0, 0, 0);
    }
    float* pp = part + (size_t)blockIdx.x * 2304;
    #pragma unroll
    for (int mt = 0; mt < 3; ++mt)
        #pragma unroll
        for (int nt = 0; nt < 3; ++nt)
            #pragma unroll
            for (int r = 0; r < 4; ++r)
                pp[(mt * 16 + hi * 4 + r) * 48 + nt * 16 + lo] = acc[mt][nt][r];
}

// ---------------- fused gram-reduce + l2norm + temperature + softmax ----------------
__global__ __launch_bounds__(64) void gram_softmax_k(const float* __restrict__ part,
                                                     const float* __restrict__ norm2p,
                                                     const float* __restrict__ temp,
                                                     float* __restrict__ attn) {
    const int row = blockIdx.x;            // 0..191
    const int h = row / CHD, r = row % CHD;
    const int d = threadIdx.x;
    float s = 0.f;
    if (d < CHD) {
        const float* pp = part + (size_t)h * GNB * 2304 + r * 48 + d;
        for (int nb = 0; nb < GNB; ++nb) s += pp[(size_t)nb * 2304];
    }
    float v = -1e30f;
    if (d < CHD) {
        float qn = fmaxf(sqrtf(norm2p[2 * row] + norm2p[2 * row + 1]), 1e-12f);
        int kc = CIN + h * CHD + d;
        float kn = fmaxf(sqrtf(norm2p[2 * kc] + norm2p[2 * kc + 1]), 1e-12f);
        v = temp[h] * s / (qn * kn);
    }
    float mx = v;
    #pragma unroll
    for (int o = 32; o > 0; o >>= 1) mx = fmaxf(mx, __shfl_xor(mx, o));
    float e = (d < CHD) ? expf(v - mx) : 0.f;
    float se = e;
    #pragma unroll
    for (int o = 32; o > 0; o >>= 1) se += __shfl_xor(se, o);
    if (d < CHD) attn[row * CHD + d] = e / se;
}

// ---------------- M = proj_w @ blockdiag(attn) : bf16 [256][192], zero-padded ----------------
__global__ void mmat_k(const float* __restrict__ proj_w, const float* __restrict__ attn,
                       u16* __restrict__ Mb) {
    int idx = blockIdx.x * blockDim.x + threadIdx.x;
    if (idx >= 256 * CIN) return;
    int o = idx / CIN, j = idx % CIN;
    float s = 0.f;
    if (o < CIN) {
        int h = j / CHD, d = j % CHD;
        for (int c = 0; c < CHD; ++c)
            s += proj_w[o * CIN + h * CHD + c] * attn[(h * CHD + c) * CHD + d];
    }
    Mb[idx] = f2bh(s);
}

extern "C" void kernel_launch(void* const* d_in, const int* in_sizes, int n_in,
                              void* d_out, int out_size, void* d_ws, size_t ws_size,
                              hipStream_t stream) {
    const float* x       = (const float*)d_in[0];
    const float* ln1w    = (const float*)d_in[1];
    const float* ln1b    = (const float*)d_in[2];
    const float* qkv_w   = (const float*)d_in[3];
    const float* qkv_dw  = (const float*)d_in[4];
    const float* proj_w  = (const float*)d_in[5];
    const float* temp    = (const float*)d_in[6];
    const float* ln2w    = (const float*)d_in[7];
    const float* ln2b    = (const float*)d_in[8];
    const float* pin_w   = (const float*)d_in[9];
    const float* ffn_dw  = (const float*)d_in[10];
    const float* pout_w  = (const float*)d_in[11];
    float* out = (float*)d_out;

    // workspace layout
    char* wsb = (char*)d_ws;
    size_t off = 0;
    auto alloc = [&](size_t bytes) {
        void* p = wsb + off; off += (bytes + 255) & ~(size_t)255; return p;
    };
    float* norm2p  = (float*)alloc(C3 * 2 * 4);
    float* attn    = (float*)alloc(NHEADS * 2304 * 4);
    float* part    = (float*)alloc((size_t)NHEADS * GNB * 2304 * 4);
    u16*   qkv_wb  = (u16*)alloc((size_t)640 * 192 * 2);
    u16*   pin_wb  = (u16*)alloc((size_t)1024 * 192 * 2);
    u16*   pout_wb = (u16*)alloc((size_t)256 * 512 * 2);
    u16*   M_b     = (u16*)alloc((size_t)256 * 192 * 2);
    u16*   xn1_t   = (u16*)alloc((size_t)NPOS * 192 * 2);
    u16*   yn2_t   = (u16*)alloc((size_t)NPOS * 192 * 2);
    u16*   ybuf    = (u16*)alloc((size_t)CIN * NPOS * 2);   // y residual, bf16
    u16*   regionA = (u16*)alloc((size_t)1024 * NPOS * 2);  // qkv_raw -> h_raw
    u16*   regionB = (u16*)alloc((size_t)1024 * NPOS * 2);  // qkv_conv -> g512
    u16* qkv_raw  = regionA;
    u16* qkv_conv = regionB;
    u16* h_raw    = regionA;
    u16* g512     = regionB;                                // rows 510,511 zeroed

    // 0. weight conversions (single launch, bf16, zero-padded to tile multiples)
    cvtw_k<<<(CVT_N1 + CVT_N2 + CVT_N3 + 255) / 256, 256, 0, stream>>>(
        qkv_w, pin_w, pout_w, qkv_wb, pin_wb, pout_wb);
    // 1. LN1 + transpose -> xn1_t [N][192] bf16
    lnt_k<float><<<NPOS / 64, 256, 0, stream>>>(x, ln1w, ln1b, xn1_t);
    // 2. qkv = qkv_w @ LN1(x)   [576][N] bf16 (m-fastest grid: B-tile L2 reuse)
    gemm_mfma_k<192, u16, float, false><<<dim3(5, NPOS / 128), 256, 0, stream>>>(
        qkv_wb, xn1_t, C3, nullptr, qkv_raw);
    // 3. depthwise conv qkv (+ fused q,k row sum-of-squares partials)
    dwconv_k<<<C3 * 2, 256, 0, stream>>>(qkv_raw, qkv_conv, qkv_dw, norm2p);
    // 4. gram S = q k^T (MFMA partials)
    gram_k<<<NHEADS * GNB, 64, 0, stream>>>(qkv_conv, part);
    // 5. fused reduce + softmax (l2-norm + temperature folded in)
    gram_softmax_k<<<192, 64, 0, stream>>>(part, norm2p, temp, attn);
    // 6. M = proj_w @ blockdiag(attn), bf16 padded directly
    mmat_k<<<(256 * CIN + 255) / 256, 256, 0, stream>>>(proj_w, attn, M_b);
    // 7. y = x + M @ v   (B = v in [C][N], transposed in-kernel; m-fastest grid)
    gemm_bt_k<192, u16, float, true><<<dim3(2, NPOS / 128), 256, 0, stream>>>(
        M_b, qkv_conv + (size_t)384 * NPOS, CIN, x, ybuf);
    // 8. LN2 + transpose -> yn2_t (bf16 input)
    lnt_k<u16><<<NPOS / 64, 256, 0, stream>>>(ybuf, ln2w, ln2b, yn2_t);
    // 9. h = pin_w @ LN2(y)   [1024][N] bf16 (m-fastest grid: B-tile L2 reuse)
    gemm_mfma_k<192, u16, float, false><<<dim3(8, NPOS / 128), 256, 0, stream>>>(
        pin_wb, yn2_t, 1024, nullptr, h_raw);
    // 10. barrier-free fused depthwise conv pair + gelu gate -> g512 [512][N]
    dwconv_glu3_k<<<(HF + 2) * 4, 256, 0, stream>>>(h_raw, g512, ffn_dw);
    // 11. out = y + pout_w @ g   (B = g in [C][N], transposed in-kernel)
    gemm_bt_k<512, float, u16, true><<<dim3(2, NPOS / 128), 256, 0, stream>>>(
        pout_wb, g512, CIN, ybuf, out);
}

// Round 13
// 216.075 us; speedup vs baseline: 1.0638x; 1.0638x over previous
//
#include <hip/hip_runtime.h>
#include <math.h>

// Problem constants
#define NPOS 40960      // T*H*W
#define TT 10
#define HH 64
#define WW 64
#define HWP 4096        // H*W
#define CIN 192
#define C3 576
#define NHEADS 4
#define CHD 48
#define HF 510
#define GNB 80          // gram n-chunks per head
#define GCHUNK 512      // 80*512 = 40960

typedef unsigned short u16;
typedef unsigned int   u32;
typedef __bf16 bf16x8 __attribute__((ext_vector_type(8)));
typedef __bf16 bf16x2 __attribute__((ext_vector_type(2)));
typedef float  f32x4  __attribute__((ext_vector_type(4)));
typedef u16    u16x8  __attribute__((ext_vector_type(8)));
typedef u16    u16x4  __attribute__((ext_vector_type(4)));
typedef u32    u32x4  __attribute__((ext_vector_type(4)));
typedef u32    u32x2  __attribute__((ext_vector_type(2)));

__device__ __forceinline__ float b2f(u16 u) {
    return __uint_as_float(((unsigned int)u) << 16);
}
// integer RNE: used for block-uniform values (stays on SALU -> weights in SGPR)
__device__ __forceinline__ u16 f2b(float f) {
    unsigned int i = __float_as_uint(f);
    unsigned int r = (i + 0x7FFFu + ((i >> 16) & 1u)) >> 16;   // RNE
    return (u16)r;
}
// HW cvt: per-lane stores; compiler pairs adjacent casts into v_cvt_pk_bf16_f32 (RNE)
__device__ __forceinline__ u16 f2bh(float f) {
    return __builtin_bit_cast(u16, static_cast<__bf16>(f));
}
// branch-free gelu: Abramowitz-Stegun 7.1.26 erf (|abs err| <= 1.5e-7, far below
// bf16 rounding). Uses native v_rcp_f32 + v_exp_f32 (~17 VALU, no branches).
__device__ __forceinline__ float gelu_fast(float v) {
    float z = fabsf(v) * 0.70710678118654752f;
    float d = fmaf(0.3275911f, z, 1.0f);
#if __has_builtin(__builtin_amdgcn_rcpf)
    float t = __builtin_amdgcn_rcpf(d);
#else
    float t = 1.0f / d;
#endif
    float p = fmaf(1.061405429f, t, -1.453152027f);
    p = fmaf(p, t, 1.421413741f);
    p = fmaf(p, t, -0.284496736f);
    p = fmaf(p, t, 0.254829592f);
    p = p * t;
    float e = __expf(-z * z);
    float E = fmaf(-p, e, 1.0f);          // erf(z), z >= 0
    return 0.5f * v * (1.0f + copysignf(E, v));
}

// packed bf16 pair dot-product with f32 accumulate; HW v_dot2_f32_bf16 if available
__device__ __forceinline__ float dot2bf(u32 a, u32 b, float c) {
#if __has_builtin(__builtin_amdgcn_fdot2_f32_bf16)
    return __builtin_amdgcn_fdot2_f32_bf16(
        __builtin_bit_cast(bf16x2, a), __builtin_bit_cast(bf16x2, b), c, false);
#else
    float a0 = b2f((u16)(a & 0xffffu)), a1 = b2f((u16)(a >> 16));
    float b0 = b2f((u16)(b & 0xffffu)), b1 = b2f((u16)(b >> 16));
    return fmaf(a1, b1, fmaf(a0, b0, c));
#endif
}
__device__ __forceinline__ u32 alignp(u32 hi, u32 lo) {
#if __has_builtin(__builtin_amdgcn_alignbit)
    return __builtin_amdgcn_alignbit(hi, lo, 16);
#else
    return (lo >> 16) | (hi << 16);
#endif
}

// VALU lane-neighbor exchange via DPP. row_shr:1 (0x111): dst lane n = src lane n-1;
// row_shl:1 (0x101): dst lane n = src lane n+1. bound_ctrl=1 zeroes at the 16-lane
// row boundaries.
__device__ __forceinline__ u32 dpp_prev(u32 v) {
#if __has_builtin(__builtin_amdgcn_update_dpp)
    return (u32)__builtin_amdgcn_update_dpp(0, (int)v, 0x111, 0xF, 0xF, true);
#else
    int l = (int)(threadIdx.x & 63);
    u32 r = __shfl(v, l - 1);
    return ((l & 15) == 0) ? 0u : r;
#endif
}
__device__ __forceinline__ u32 dpp_next(u32 v) {
#if __has_builtin(__builtin_amdgcn_update_dpp)
    return (u32)__builtin_amdgcn_update_dpp(0, (int)v, 0x101, 0xF, 0xF, true);
#else
    int l = (int)(threadIdx.x & 63);
    u32 r = __shfl(v, l + 1);
    return ((l & 15) == 15) ? 0u : r;
#endif
}
__device__ __forceinline__ u32 dpp_prev8(u32 v, bool edge) {
    u32 r = dpp_prev(v);
    return edge ? 0u : r;
}
__device__ __forceinline__ u32 dpp_next8(u32 v, bool edge) {
    u32 r = dpp_next(v);
    return edge ? 0u : r;
}

// async global->LDS, 16B per lane; lds base must be wave-uniform
#define GLD_LDS16(g, l) __builtin_amdgcn_global_load_lds( \
    (const __attribute__((address_space(1))) void*)(g), \
    (__attribute__((address_space(3))) void*)(l), 16, 0, 0)

// ---------------- combined weight convert fp32 -> bf16 with zero padding ----------------
#define CVT_N1 (640 * 192)
#define CVT_N2 (1024 * 192)
#define CVT_N3 (256 * 512)
__global__ void cvtw_k(const float* __restrict__ qkv_w, const float* __restrict__ pin_w,
                       const float* __restrict__ pout_w,
                       u16* __restrict__ qkv_wb, u16* __restrict__ pin_wb,
                       u16* __restrict__ pout_wb) {
    int idx = blockIdx.x * 256 + threadIdx.x;
    if (idx < CVT_N1) {
        int r = idx / 192, c = idx % 192;
        qkv_wb[idx] = f2bh(r < 576 ? qkv_w[r * 192 + c] : 0.f);
    } else if (idx < CVT_N1 + CVT_N2) {
        int k = idx - CVT_N1;
        int r = k / 192, c = k % 192;
        pin_wb[k] = f2bh(r < 1020 ? pin_w[r * 192 + c] : 0.f);
    } else if (idx < CVT_N1 + CVT_N2 + CVT_N3) {
        int k = idx - CVT_N1 - CVT_N2;
        int r = k / 512, c = k % 512;
        pout_wb[k] = f2bh((r < 192 && c < 510) ? pout_w[r * 510 + c] : 0.f);
    }
}

// ---------------- fused LN (over C) + transpose to [N][192] bf16 ----------------
template<typename InT>
__global__ __launch_bounds__(256) void lnt_k(const InT* __restrict__ X,
                                             const float* __restrict__ w,
                                             const float* __restrict__ b,
                                             u16* __restrict__ Xt) {
    __shared__ float sm[CIN][65];
    __shared__ float ps[4][64], ps2[4][64];
    __shared__ float smean[64], srstd[64];
    __shared__ float sw[CIN], sb[CIN];
    const int tid = threadIdx.x;
    const int n0 = blockIdx.x * 64;
    if (tid < CIN) { sw[tid] = w[tid]; sb[tid] = b[tid]; }
    if constexpr (sizeof(InT) == 4) {
        #pragma unroll
        for (int i = 0; i < 12; ++i) {
            int e = i * 256 + tid;
            int c = e >> 4, p4 = (e & 15) * 4;
            float4 v = *(const float4*)((const float*)X + (size_t)c * NPOS + n0 + p4);
            sm[c][p4 + 0] = v.x; sm[c][p4 + 1] = v.y;
            sm[c][p4 + 2] = v.z; sm[c][p4 + 3] = v.w;
        }
    } else {
        #pragma unroll
        for (int i = 0; i < 6; ++i) {
            int e = i * 256 + tid;
            int c = e >> 3, p8 = (e & 7) * 8;
            u16x8 v = *(const u16x8*)((const u16*)X + (size_t)c * NPOS + n0 + p8);
            #pragma unroll
            for (int j = 0; j < 8; ++j) sm[c][p8 + j] = b2f(v[j]);
        }
    }
    __syncthreads();
    int g = tid >> 6, nn = tid & 63;
    float s = 0.f, s2 = 0.f;
    for (int c = g * 48; c < g * 48 + 48; ++c) {
        float v = sm[c][nn];
        s += v; s2 += v * v;
    }
    ps[g][nn] = s; ps2[g][nn] = s2;
    __syncthreads();
    if (g == 0) {
        float t = ps[0][nn] + ps[1][nn] + ps[2][nn] + ps[3][nn];
        float t2 = ps2[0][nn] + ps2[1][nn] + ps2[2][nn] + ps2[3][nn];
        float m = t / CIN;
        float var = t2 / CIN - m * m;
        smean[nn] = m;
        srstd[nn] = rsqrtf(var + 1e-5f);
    }
    __syncthreads();
    #pragma unroll
    for (int i = 0; i < 6; ++i) {
        int e = i * 256 + tid;
        int nl = e / 24, cg = e % 24;
        int c0 = cg * 8;
        float m = smean[nl], rs_ = srstd[nl];
        u16x8 o;
        #pragma unroll
        for (int j = 0; j < 8; ++j) {
            float v = (sm[c0 + j][nl] - m) * rs_ * sw[c0 + j] + sb[c0 + j];
            o[j] = f2bh(v);
        }
        *(u16x8*)(Xt + (size_t)(n0 + nl) * CIN + c0) = o;
    }
}

// ---------------- MFMA GEMM, LDS double-buffered (m97 structure) ----------------
// out[o][n] = sum_k A[o][k]*Bt[n][k] (+resid). Tile 128x128, BK=32. Bt is [N][KP].
// 1-D grid + XCD-chunked mapping: blocks dispatch round-robin to XCDs (bid&7), so
// blocks sharing one B-tile (same n, all MB m-rounds) are placed 8 apart ->
// SAME XCD -> B hits that XCD's L2 after the first m-round. Different XCDs own
// disjoint n-chunks. (Round-12's plain m-fastest grid put the sharing blocks on
// 8 different non-coherent L2s and regressed.) Grid size must be divisible by 8.
template<int KP, typename OutT, typename ResT, bool RESID>
__global__ __launch_bounds__(256) void gemm_mfma_k(
    const u16* __restrict__ A, const u16* __restrict__ Bt, int O,
    const ResT* __restrict__ resid, OutT* __restrict__ outp)
{
    constexpr int NT = KP / 32;
    __shared__ u16 As[2][128 * 32];
    __shared__ u16 Bs[2][128 * 32];
    const int tid  = threadIdx.x;
    const int lane = tid & 63;
    const int wv   = tid >> 6;
    const int lo = lane & 15, hi = lane >> 4;
    // XCD-chunked (m,n) mapping
    const int MB = (O + 127) >> 7;
    const int bid = blockIdx.x;
    const int w = (bid & 7) * ((int)gridDim.x >> 3) + (bid >> 3);
    const int m_blk = (w % MB) * 128;
    const int n_blk = (w / MB) * 128;

    int bb0 = (0 * 4 + wv) * 1024 + lane * 16;
    int bb1 = (1 * 4 + wv) * 1024 + lane * 16;
    const int r0 = bb0 >> 6, c80 = (bb0 >> 4) & 3;
    const int r1 = bb1 >> 6, c81 = (bb1 >> 4) & 3;

    auto stage = [&](int buf, int k0) {
        GLD_LDS16(A  + (size_t)(m_blk + r0) * KP + k0 + c80 * 8, (char*)&As[buf][0] + (0 * 4 + wv) * 1024);
        GLD_LDS16(A  + (size_t)(m_blk + r1) * KP + k0 + c81 * 8, (char*)&As[buf][0] + (1 * 4 + wv) * 1024);
        GLD_LDS16(Bt + (size_t)(n_blk + r0) * KP + k0 + c80 * 8, (char*)&Bs[buf][0] + (0 * 4 + wv) * 1024);
        GLD_LDS16(Bt + (size_t)(n_blk + r1) * KP + k0 + c81 * 8, (char*)&Bs[buf][0] + (1 * 4 + wv) * 1024);
    };

    f32x4 acc[4][4];
    const f32x4 zero = {0.f, 0.f, 0.f, 0.f};
    #pragma unroll
    for (int mt = 0; mt < 4; ++mt)
        #pragma unroll
        for (int nt = 0; nt < 4; ++nt) acc[mt][nt] = zero;

    stage(0, 0);
    __syncthreads();

    #pragma unroll
    for (int t = 0; t < NT; ++t) {
        if (t + 1 < NT) stage((t + 1) & 1, (t + 1) * 32);
        const u16* Ab = &As[t & 1][0] + (wv & 1) * 64 * 32;
        const u16* Bb = &Bs[t & 1][0] + (wv >> 1) * 64 * 32;
        bf16x8 a[4], b[4];
        #pragma unroll
        for (int q = 0; q < 4; ++q) {
            a[q] = *(const bf16x8*)(Ab + (q * 16 + lo) * 32 + hi * 8);
            b[q] = *(const bf16x8*)(Bb + (q * 16 + lo) * 32 + hi * 8);
        }
        #pragma unroll
        for (int mt = 0; mt < 4; ++mt)
            #pragma unroll
            for (int nt = 0; nt < 4; ++nt)
                acc[mt][nt] = __builtin_amdgcn_mfma_f32_16x16x32_bf16(
                    a[mt], b[nt], acc[mt][nt], 0, 0, 0);
        __syncthreads();
    }

    const int m_base = m_blk + (wv & 1) * 64;
    const int n_base = n_blk + (wv >> 1) * 64;
    #pragma unroll
    for (int mt = 0; mt < 4; ++mt) {
        #pragma unroll
        for (int r = 0; r < 4; ++r) {
            int m = m_base + mt * 16 + hi * 4 + r;
            if (m < O) {
                size_t rowoff = (size_t)m * NPOS;
                #pragma unroll
                for (int nt = 0; nt < 4; ++nt) {
                    int n = n_base + nt * 16 + lo;
                    float v = acc[mt][nt][r];
                    if (RESID) {
                        if constexpr (sizeof(ResT) == 2) v += b2f(((const u16*)resid)[rowoff + n]);
                        else                             v += ((const float*)resid)[rowoff + n];
                    }
                    if constexpr (sizeof(OutT) == 2) outp[rowoff + n] = (OutT)f2bh(v);
                    else                             outp[rowoff + n] = (OutT)v;
                }
            }
        }
    }
}

// ---------------- MFMA GEMM with in-kernel B transpose (B given as [K][N]) --------
// out[o][n] = sum_k A[o][k]*B[k][n] (+resid). Per K-step the 32x128 B-tile is read
// COALESCED from [K][N] rows, written transposed into LDS with k-block XOR swizzle.
// Grid dim3(N_blocks, M_blocks): n fastest (round-9 proven layout; only 2 m-rounds).
template<int KP, typename OutT, typename ResT, bool RESID>
__global__ __launch_bounds__(256) void gemm_bt_k(
    const u16* __restrict__ A, const u16* __restrict__ Bkn, int O,
    const ResT* __restrict__ resid, OutT* __restrict__ outp)
{
    constexpr int NT = KP / 32;
    __shared__ u16 As[2][128 * 32];
    __shared__ u16 Bs[2][128 * 32];
    const int tid  = threadIdx.x;
    const int lane = tid & 63;
    const int wv   = tid >> 6;
    const int lo = lane & 15, hi = lane >> 4;
    const int m_blk = blockIdx.y * 128;
    const int n_blk = blockIdx.x * 128;

    int bb0 = (0 * 4 + wv) * 1024 + lane * 16;
    int bb1 = (1 * 4 + wv) * 1024 + lane * 16;
    const int r0 = bb0 >> 6, c80 = (bb0 >> 4) & 3;
    const int r1 = bb1 >> 6, c81 = (bb1 >> 4) & 3;
    auto stageA = [&](int buf, int k0) {
        GLD_LDS16(A + (size_t)(m_blk + r0) * KP + k0 + c80 * 8, (char*)&As[buf][0] + (0 * 4 + wv) * 1024);
        GLD_LDS16(A + (size_t)(m_blk + r1) * KP + k0 + c81 * 8, (char*)&As[buf][0] + (1 * 4 + wv) * 1024);
    };

    const int kp2 = (tid & 15) * 2;        // 0,2,..,30
    const int nf  = (tid >> 4) * 8;        // 0..120
    const int kb  = kp2 >> 3;              // k-block 0..3
    const int klo = kp2 & 7;               // even
    u16x8 bv0, bv1;
    auto loadB = [&](int k0) {
        const u16* sp = Bkn + (size_t)(k0 + kp2) * NPOS + n_blk + nf;
        bv0 = *(const u16x8*)(sp);
        bv1 = *(const u16x8*)(sp + NPOS);
    };
    auto writeB = [&](int buf) {
        #pragma unroll
        for (int i = 0; i < 8; ++i) {
            int n = nf + i;
            int idx = n * 32 + ((kb ^ ((n >> 4) & 3)) << 3) + klo;
            u32 pk = (u32)bv0[i] | ((u32)bv1[i] << 16);
            *(u32*)&Bs[buf][idx] = pk;
        }
    };

    f32x4 acc[4][4];
    const f32x4 zero = {0.f, 0.f, 0.f, 0.f};
    #pragma unroll
    for (int mt = 0; mt < 4; ++mt)
        #pragma unroll
        for (int nt = 0; nt < 4; ++nt) acc[mt][nt] = zero;

    stageA(0, 0);
    loadB(0);
    writeB(0);
    __syncthreads();

    #pragma unroll
    for (int t = 0; t < NT; ++t) {
        if (t + 1 < NT) { stageA((t + 1) & 1, (t + 1) * 32); loadB((t + 1) * 32); }
        const u16* Ab = &As[t & 1][0] + (wv & 1) * 64 * 32;
        const u16* Bb = &Bs[t & 1][0] + (wv >> 1) * 64 * 32;
        bf16x8 a[4], b[4];
        #pragma unroll
        for (int q = 0; q < 4; ++q) {
            a[q] = *(const bf16x8*)(Ab + (q * 16 + lo) * 32 + hi * 8);
            b[q] = *(const bf16x8*)(Bb + (q * 16 + lo) * 32 + ((hi ^ (q & 3)) * 8));
        }
        #pragma unroll
        for (int mt = 0; mt < 4; ++mt)
            #pragma unroll
            for (int nt = 0; nt < 4; ++nt)
                acc[mt][nt] = __builtin_amdgcn_mfma_f32_16x16x32_bf16(
                    a[mt], b[nt], acc[mt][nt], 0, 0, 0);
        if (t + 1 < NT) writeB((t + 1) & 1);
        __syncthreads();
    }

    const int m_base = m_blk + (wv & 1) * 64;
    const int n_base = n_blk + (wv >> 1) * 64;
    #pragma unroll
    for (int mt = 0; mt < 4; ++mt) {
        #pragma unroll
        for (int r = 0; r < 4; ++r) {
            int m = m_base + mt * 16 + hi * 4 + r;
            if (m < O) {
                size_t rowoff = (size_t)m * NPOS;
                #pragma unroll
                for (int nt = 0; nt < 4; ++nt) {
                    int n = n_base + nt * 16 + lo;
                    float v = acc[mt][nt][r];
                    if (RESID) {
                        if constexpr (sizeof(ResT) == 2) v += b2f(((const u16*)resid)[rowoff + n]);
                        else                             v += ((const float*)resid)[rowoff + n];
                    }
                    if constexpr (sizeof(OutT) == 2) outp[rowoff + n] = (OutT)f2bh(v);
                    else                             outp[rowoff + n] = (OutT)v;
                }
            }
        }
    }
}

// ---------------- Depthwise 3x3x3 conv, padding=1, bf16 in/out ----------------
// Equilibrium form (8 structural variants all land at 46-52us): DPP neighbor
// exchange, 2-slice-deep prefetch, no in-loop barriers, fused norm partials.
__global__ __launch_bounds__(256) void dwconv_k(const u16* __restrict__ in,
                                                u16* __restrict__ outp,
                                                const float* __restrict__ wgt,
                                                float* __restrict__ nrm2)
{
    __shared__ float red[256];
    const int lane = threadIdx.x & 63;
    const int wv   = threadIdx.x >> 6;
    const int c    = blockIdx.x >> 1;
    const int hb   = blockIdx.x & 1;
    const int h    = hb * 32 + wv * 8 + (lane >> 3);
    const int w0c  = (lane & 7) * 8;
    const bool wl0 = (lane & 7) == 0;
    const bool wl7 = (lane & 7) == 7;
    const bool hup = (h > 0), hdn = (h < HH - 1);
    u32 W01[9], W2h[9];
    {
        const float* wc = wgt + c * 27;
        #pragma unroll
        for (int i = 0; i < 9; ++i) {
            float a = wc[i * 3 + 0], b = wc[i * 3 + 1], d = wc[i * 3 + 2];
            W01[i] = (u32)f2b(a) | ((u32)f2b(b) << 16);
            W2h[i] = ((u32)f2b(d)) << 16;
        }
    }
    const u16* base = in   + (size_t)c * (TT * HWP);
    u16*       ob   = outp + (size_t)c * (TT * HWP);

    u32x4 zv = {0u, 0u, 0u, 0u};
    u32x4 ld[3][3];
    auto issue = [&](int ph, int ts) {
        const u16* rp = base + (size_t)ts * HWP + h * WW + w0c;
        ld[ph][0] = hup ? *(const u32x4*)(rp - WW) : zv;
        ld[ph][1] = *(const u32x4*)(rp);
        ld[ph][2] = hdn ? *(const u32x4*)(rp + WW) : zv;
    };

    float acc[3][8];
    #pragma unroll
    for (int o_ = 0; o_ < 3; ++o_)
        #pragma unroll
        for (int j = 0; j < 8; ++j) acc[o_][j] = 0.f;
    float sq = 0.f;

    issue(0, 0);
    issue(1, 1);
    #pragma unroll
    for (int ts = 0; ts < TT; ++ts) {
        const int cb = ts % 3;
        if (ts + 2 < TT) issue((ts + 2) % 3, ts + 2);
        #pragma unroll
        for (int dh = 0; dh < 3; ++dh) {
            u32 P0 = ld[cb][dh][0], P1 = ld[cb][dh][1];
            u32 P2 = ld[cb][dh][2], P3 = ld[cb][dh][3];
            u32 Pm = dpp_prev8(P3, wl0);
            u32 Pp = dpp_next8(P0, wl7);
            u32 S0 = alignp(P0, Pm), S1 = alignp(P1, P0);
            u32 S2 = alignp(P2, P1), S3 = alignp(P3, P2);
            u32 S4 = alignp(Pp, P3);
            #pragma unroll
            for (int tp = 0; tp < 3; ++tp) {
                int o_;
                if (tp == 2) { if (ts < 1) continue; o_ = (ts - 1) % 3; }
                else if (tp == 1) { o_ = ts % 3; }
                else { if (ts + 1 >= TT) continue; o_ = (ts + 1) % 3; }
                const u32 wA = W01[tp * 3 + dh], wB = W2h[tp * 3 + dh];
                float* ap = acc[o_];
                ap[0] = dot2bf(S0, wA, ap[0]); ap[0] = dot2bf(P0, wB, ap[0]);
                ap[1] = dot2bf(P0, wA, ap[1]); ap[1] = dot2bf(S1, wB, ap[1]);
                ap[2] = dot2bf(S1, wA, ap[2]); ap[2] = dot2bf(P1, wB, ap[2]);
                ap[3] = dot2bf(P1, wA, ap[3]); ap[3] = dot2bf(S2, wB, ap[3]);
                ap[4] = dot2bf(S2, wA, ap[4]); ap[4] = dot2bf(P2, wB, ap[4]);
                ap[5] = dot2bf(P2, wA, ap[5]); ap[5] = dot2bf(S3, wB, ap[5]);
                ap[6] = dot2bf(S3, wA, ap[6]); ap[6] = dot2bf(P3, wB, ap[6]);
                ap[7] = dot2bf(P3, wA, ap[7]); ap[7] = dot2bf(S4, wB, ap[7]);
            }
        }
        if (ts >= 1) {
            const int o_ = (ts - 1) % 3;
            u16x8 o;
            #pragma unroll
            for (int j = 0; j < 8; ++j) {
                float v = acc[o_][j];
                sq = fmaf(v, v, sq);
                o[j] = f2bh(v);
            }
            *(u16x8*)(ob + (size_t)(ts - 1) * HWP + h * WW + w0c) = o;
            #pragma unroll
            for (int j = 0; j < 8; ++j) acc[o_][j] = 0.f;
        }
    }
    {
        const int o_ = (TT - 1) % 3;
        u16x8 o;
        #pragma unroll
        for (int j = 0; j < 8; ++j) {
            float v = acc[o_][j];
            sq = fmaf(v, v, sq);
            o[j] = f2bh(v);
        }
        *(u16x8*)(ob + (size_t)(TT - 1) * HWP + h * WW + w0c) = o;
    }
    if (nrm2) {
        red[threadIdx.x] = sq;
        __syncthreads();
        for (int off = 128; off > 0; off >>= 1) {
            if (threadIdx.x < off) red[threadIdx.x] += red[threadIdx.x + off];
            __syncthreads();
        }
        if (threadIdx.x == 0) nrm2[c * 2 + hb] = red[0];
    }
}

// ---------------- FFN: fused depthwise conv pair + gelu gate, BARRIER-FREE ----------------
// cpr in 0..511: cpr >= HF writes zero rows (510,511) so the padded K=512 GEMM
// staging reads zeros.
__global__ __launch_bounds__(256) void dwconv_glu3_k(const u16* __restrict__ in,
                                                     u16* __restrict__ gout,
                                                     const float* __restrict__ wgt)
{
    const int lane = threadIdx.x & 63;
    const int wv   = threadIdx.x >> 6;     // 0..3
    const int cpr  = blockIdx.x >> 2;      // 0..511
    const int hb   = blockIdx.x & 3;
    const int h    = hb * 16 + wv * 4 + (lane >> 4);
    const int w0c  = (lane & 15) * 4;
    u16* ob = gout + (size_t)cpr * (TT * HWP);
    if (cpr >= HF) {                       // zero-pad rows 510,511
        u16x4 z = {0, 0, 0, 0};
        #pragma unroll
        for (int ts = 0; ts < TT; ++ts)
            *(u16x4*)(ob + (size_t)ts * HWP + h * WW + w0c) = z;
        return;
    }
    const bool hup = (h > 0), hdn = (h < HH - 1);

    u32 W01[2][9], W2h[2][9];
    #pragma unroll
    for (int ch = 0; ch < 2; ++ch) {
        const float* wc = wgt + (size_t)(cpr + ch * HF) * 27;
        #pragma unroll
        for (int i = 0; i < 9; ++i) {
            float a = wc[i * 3 + 0], b = wc[i * 3 + 1], d = wc[i * 3 + 2];
            W01[ch][i] = (u32)f2b(a) | ((u32)f2b(b) << 16);
            W2h[ch][i] = ((u32)f2b(d)) << 16;
        }
    }
    const u16* base0 = in + (size_t)cpr * (TT * HWP);
    const u16* base1 = in + (size_t)(cpr + HF) * (TT * HWP);

    u32x2 zv = {0u, 0u};
    u32x2 ld[2][3][3];
    auto issue = [&](int ph, int ts) {
        const u16* rp0 = base0 + (size_t)ts * HWP + h * WW + w0c;
        ld[0][ph][0] = hup ? *(const u32x2*)(rp0 - WW) : zv;
        ld[0][ph][1] = *(const u32x2*)(rp0);
        ld[0][ph][2] = hdn ? *(const u32x2*)(rp0 + WW) : zv;
        const u16* rp1 = base1 + (size_t)ts * HWP + h * WW + w0c;
        ld[1][ph][0] = hup ? *(const u32x2*)(rp1 - WW) : zv;
        ld[1][ph][1] = *(const u32x2*)(rp1);
        ld[1][ph][2] = hdn ? *(const u32x2*)(rp1 + WW) : zv;
    };

    float acc[2][3][4];
    #pragma unroll
    for (int ch = 0; ch < 2; ++ch)
        #pragma unroll
        for (int o_ = 0; o_ < 3; ++o_)
            #pragma unroll
            for (int j = 0; j < 4; ++j) acc[ch][o_][j] = 0.f;

    auto emit = [&](int ots) {
        const int o_ = ots % 3;
        u16x4 o;
        #pragma unroll
        for (int j = 0; j < 4; ++j)
            o[j] = f2bh(gelu_fast(acc[0][o_][j]) * acc[1][o_][j]);
        *(u16x4*)(ob + (size_t)ots * HWP + h * WW + w0c) = o;
        #pragma unroll
        for (int j = 0; j < 4; ++j) { acc[0][o_][j] = 0.f; acc[1][o_][j] = 0.f; }
    };

    issue(0, 0);
    issue(1, 1);
    #pragma unroll
    for (int ts = 0; ts < TT; ++ts) {
        const int cb = ts % 3;
        if (ts + 2 < TT) issue((ts + 2) % 3, ts + 2);
        #pragma unroll
        for (int ch = 0; ch < 2; ++ch) {
            #pragma unroll
            for (int dh = 0; dh < 3; ++dh) {
                u32 P0 = ld[ch][cb][dh][0], P1 = ld[ch][cb][dh][1];
                u32 Pm = dpp_prev(P1);
                u32 Pp = dpp_next(P0);
                u32 S0 = alignp(P0, Pm), S1 = alignp(P1, P0), S2 = alignp(Pp, P1);
                #pragma unroll
                for (int tp = 0; tp < 3; ++tp) {
                    int o_;
                    if (tp == 2) { if (ts < 1) continue; o_ = (ts - 1) % 3; }
                    else if (tp == 1) { o_ = ts % 3; }
                    else { if (ts + 1 >= TT) continue; o_ = (ts + 1) % 3; }
                    const u32 wA = W01[ch][tp * 3 + dh], wB = W2h[ch][tp * 3 + dh];
                    float* ap = acc[ch][o_];
                    ap[0] = dot2bf(S0, wA, ap[0]); ap[0] = dot2bf(P0, wB, ap[0]);
                    ap[1] = dot2bf(P0, wA, ap[1]); ap[1] = dot2bf(S1, wB, ap[1]);
                    ap[2] = dot2bf(S1, wA, ap[2]); ap[2] = dot2bf(P1, wB, ap[2]);
                    ap[3] = dot2bf(P1, wA, ap[3]); ap[3] = dot2bf(S2, wB, ap[3]);
                }
            }
        }
        if (ts >= 1) emit(ts - 1);
    }
    emit(TT - 1);
}

// ---------------- gram partials via MFMA: part[blk][48][48] = q_chunk k_chunk^T ----------------
__global__ __launch_bounds__(64) void gram_k(const u16* __restrict__ qkv,
                                             float* __restrict__ part) {
    const int h  = blockIdx.x / GNB;
    const int nb = blockIdx.x % GNB;
    const int lane = threadIdx.x;
    const int lo = lane & 15, hi = lane >> 4;
    const u16* qp = qkv + (size_t)(h * CHD) * NPOS + (size_t)nb * GCHUNK + hi * 8;
    const u16* kp = qkv + (size_t)(CIN + h * CHD) * NPOS + (size_t)nb * GCHUNK + hi * 8;
    f32x4 acc[3][3];
    const f32x4 zero = {0.f, 0.f, 0.f, 0.f};
    #pragma unroll
    for (int mt = 0; mt < 3; ++mt)
        #pragma unroll
        for (int nt = 0; nt < 3; ++nt) acc[mt][nt] = zero;
    #pragma unroll
    for (int ks = 0; ks < GCHUNK; ks += 32) {
        bf16x8 a[3], b[3];
        #pragma unroll
        for (int t = 0; t < 3; ++t) {
            a[t] = *(const bf16x8*)(qp + (size_t)(t * 16 + lo) * NPOS + ks);
            b[t] = *(const bf16x8*)(kp + (size_t)(t * 16 + lo) * NPOS + ks);
        }
        #pragma unroll
        for (int mt = 0; mt < 3; ++mt)
            #pragma unroll
            for (int nt = 0; nt < 3; ++nt)
                acc[mt][nt] = __builtin_amdgcn_mfma_f32_16x16x32_bf16(
                    a[mt], b[nt], acc[mt][nt], 0, 0, 0);
    }
    float* pp = part + (size_t)blockIdx.x * 2304;
    #pragma unroll
    for (int mt = 0; mt < 3; ++mt)
        #pragma unroll
        for (int nt = 0; nt < 3; ++nt)
            #pragma unroll
            for (int r = 0; r < 4; ++r)
                pp[(mt * 16 + hi * 4 + r) * 48 + nt * 16 + lo] = acc[mt][nt][r];
}

// ---------------- fused gram-reduce + l2norm + temperature + softmax ----------------
__global__ __launch_bounds__(64) void gram_softmax_k(const float* __restrict__ part,
                                                     const float* __restrict__ norm2p,
                                                     const float* __restrict__ temp,
                                                     float* __restrict__ attn) {
    const int row = blockIdx.x;            // 0..191
    const int h = row / CHD, r = row % CHD;
    const int d = threadIdx.x;
    float s = 0.f;
    if (d < CHD) {
        const float* pp = part + (size_t)h * GNB * 2304 + r * 48 + d;
        for (int nb = 0; nb < GNB; ++nb) s += pp[(size_t)nb * 2304];
    }
    float v = -1e30f;
    if (d < CHD) {
        float qn = fmaxf(sqrtf(norm2p[2 * row] + norm2p[2 * row + 1]), 1e-12f);
        int kc = CIN + h * CHD + d;
        float kn = fmaxf(sqrtf(norm2p[2 * kc] + norm2p[2 * kc + 1]), 1e-12f);
        v = temp[h] * s / (qn * kn);
    }
    float mx = v;
    #pragma unroll
    for (int o = 32; o > 0; o >>= 1) mx = fmaxf(mx, __shfl_xor(mx, o));
    float e = (d < CHD) ? expf(v - mx) : 0.f;
    float se = e;
    #pragma unroll
    for (int o = 32; o > 0; o >>= 1) se += __shfl_xor(se, o);
    if (d < CHD) attn[row * CHD + d] = e / se;
}

// ---------------- M = proj_w @ blockdiag(attn) : bf16 [256][192], zero-padded ----------------
__global__ void mmat_k(const float* __restrict__ proj_w, const float* __restrict__ attn,
                       u16* __restrict__ Mb) {
    int idx = blockIdx.x * blockDim.x + threadIdx.x;
    if (idx >= 256 * CIN) return;
    int o = idx / CIN, j = idx % CIN;
    float s = 0.f;
    if (o < CIN) {
        int h = j / CHD, d = j % CHD;
        for (int c = 0; c < CHD; ++c)
            s += proj_w[o * CIN + h * CHD + c] * attn[(h * CHD + c) * CHD + d];
    }
    Mb[idx] = f2bh(s);
}

extern "C" void kernel_launch(void* const* d_in, const int* in_sizes, int n_in,
                              void* d_out, int out_size, void* d_ws, size_t ws_size,
                              hipStream_t stream) {
    const float* x       = (const float*)d_in[0];
    const float* ln1w    = (const float*)d_in[1];
    const float* ln1b    = (const float*)d_in[2];
    const float* qkv_w   = (const float*)d_in[3];
    const float* qkv_dw  = (const float*)d_in[4];
    const float* proj_w  = (const float*)d_in[5];
    const float* temp    = (const float*)d_in[6];
    const float* ln2w    = (const float*)d_in[7];
    const float* ln2b    = (const float*)d_in[8];
    const float* pin_w   = (const float*)d_in[9];
    const float* ffn_dw  = (const float*)d_in[10];
    const float* pout_w  = (const float*)d_in[11];
    float* out = (float*)d_out;

    // workspace layout
    char* wsb = (char*)d_ws;
    size_t off = 0;
    auto alloc = [&](size_t bytes) {
        void* p = wsb + off; off += (bytes + 255) & ~(size_t)255; return p;
    };
    float* norm2p  = (float*)alloc(C3 * 2 * 4);
    float* attn    = (float*)alloc(NHEADS * 2304 * 4);
    float* part    = (float*)alloc((size_t)NHEADS * GNB * 2304 * 4);
    u16*   qkv_wb  = (u16*)alloc((size_t)640 * 192 * 2);
    u16*   pin_wb  = (u16*)alloc((size_t)1024 * 192 * 2);
    u16*   pout_wb = (u16*)alloc((size_t)256 * 512 * 2);
    u16*   M_b     = (u16*)alloc((size_t)256 * 192 * 2);
    u16*   xn1_t   = (u16*)alloc((size_t)NPOS * 192 * 2);
    u16*   yn2_t   = (u16*)alloc((size_t)NPOS * 192 * 2);
    u16*   ybuf    = (u16*)alloc((size_t)CIN * NPOS * 2);   // y residual, bf16
    u16*   regionA = (u16*)alloc((size_t)1024 * NPOS * 2);  // qkv_raw -> h_raw
    u16*   regionB = (u16*)alloc((size_t)1024 * NPOS * 2);  // qkv_conv -> g512
    u16* qkv_raw  = regionA;
    u16* qkv_conv = regionB;
    u16* h_raw    = regionA;
    u16* g512     = regionB;                                // rows 510,511 zeroed

    // 0. weight conversions (single launch, bf16, zero-padded to tile multiples)
    cvtw_k<<<(CVT_N1 + CVT_N2 + CVT_N3 + 255) / 256, 256, 0, stream>>>(
        qkv_w, pin_w, pout_w, qkv_wb, pin_wb, pout_wb);
    // 1. LN1 + transpose -> xn1_t [N][192] bf16
    lnt_k<float><<<NPOS / 64, 256, 0, stream>>>(x, ln1w, ln1b, xn1_t);
    // 2. qkv = qkv_w @ LN1(x)   [576][N] bf16 (XCD-chunked 1-D grid, 5*320 blocks)
    gemm_mfma_k<192, u16, float, false><<<5 * (NPOS / 128), 256, 0, stream>>>(
        qkv_wb, xn1_t, C3, nullptr, qkv_raw);
    // 3. depthwise conv qkv (+ fused q,k row sum-of-squares partials)
    dwconv_k<<<C3 * 2, 256, 0, stream>>>(qkv_raw, qkv_conv, qkv_dw, norm2p);
    // 4. gram S = q k^T (MFMA partials)
    gram_k<<<NHEADS * GNB, 64, 0, stream>>>(qkv_conv, part);
    // 5. fused reduce + softmax (l2-norm + temperature folded in)
    gram_softmax_k<<<192, 64, 0, stream>>>(part, norm2p, temp, attn);
    // 6. M = proj_w @ blockdiag(attn), bf16 padded directly
    mmat_k<<<(256 * CIN + 255) / 256, 256, 0, stream>>>(proj_w, attn, M_b);
    // 7. y = x + M @ v   (B = v in [C][N], transposed in-kernel; n-fastest grid)
    gemm_bt_k<192, u16, float, true><<<dim3(NPOS / 128, 2), 256, 0, stream>>>(
        M_b, qkv_conv + (size_t)384 * NPOS, CIN, x, ybuf);
    // 8. LN2 + transpose -> yn2_t (bf16 input)
    lnt_k<u16><<<NPOS / 64, 256, 0, stream>>>(ybuf, ln2w, ln2b, yn2_t);
    // 9. h = pin_w @ LN2(y)   [1024][N] bf16 (XCD-chunked 1-D grid, 8*320 blocks)
    gemm_mfma_k<192, u16, float, false><<<8 * (NPOS / 128), 256, 0, stream>>>(
        pin_wb, yn2_t, 1024, nullptr, h_raw);
    // 10. barrier-free fused depthwise conv pair + gelu gate -> g512 [512][N]
    dwconv_glu3_k<<<(HF + 2) * 4, 256, 0, stream>>>(h_raw, g512, ffn_dw);
    // 11. out = y + pout_w @ g   (B = g in [C][N], transposed in-kernel; n-fastest)
    gemm_bt_k<512, float, u16, true><<<dim3(NPOS / 128, 2), 256, 0, stream>>>(
        pout_wb, g512, CIN, ybuf, out);
}